// Round 2
// baseline (583.860 us; speedup 1.0000x reference)
//
#include <hip/hip_runtime.h>
#include <math.h>

#define QSEQ 33600
#define DM 256
#define NHEADS 8

typedef __attribute__((ext_vector_type(8))) short short8;
typedef __attribute__((ext_vector_type(4))) float floatx4;

static __device__ __forceinline__ unsigned short f2bf(float f) {
  unsigned u = __float_as_uint(f);
  unsigned r = (u + 0x7FFF + ((u >> 16) & 1)) >> 16;
  return (unsigned short)r;
}
static __device__ __forceinline__ float bf2f(unsigned short s) {
  return __uint_as_float(((unsigned)s) << 16);
}

// ---------------------------------------------------------------------------
// MFMA GEMM: C[M,N] = A @ W^T + bias.
// A: [M,256] (fp32, optionally fused +A2, or bf16), W: [N,256] bf16 (pre-cvt).
// BM=64, BN=128, BK=64, 256 threads = 4 waves, wave tile 32x64 (2x4 MFMA frags).
// M % 64 == 0 (33600 = 525*64). N guarded.
// ---------------------------------------------------------------------------
template <bool A_BF16, bool OUT_BF16, bool FUSE_ADD>
__global__ __launch_bounds__(256) void gemm_mfma_kernel(
    const void* __restrict__ Ap, const float* __restrict__ A2,
    const unsigned short* __restrict__ Wb, const float* __restrict__ bias,
    void* __restrict__ Cp, int N) {
  constexpr int K = 256, BK = 64, LDA = BK + 8;  // pad 8 elems (16B)
  __shared__ unsigned short As[64 * LDA];
  __shared__ unsigned short Bs[128 * LDA];

  const int tid = threadIdx.x;
  const int m0 = blockIdx.y * 64;
  const int n0 = blockIdx.x * 128;
  const int wave = tid >> 6, lane = tid & 63;
  const int wm = wave >> 1, wn = wave & 1;
  const int l16 = lane & 15, quad = lane >> 4;

  floatx4 acc[2][4];
#pragma unroll
  for (int i = 0; i < 2; ++i)
#pragma unroll
    for (int j = 0; j < 4; ++j) acc[i][j] = (floatx4)(0.f);

  // staging indices
  const int arow = tid >> 2, aseg = tid & 3;   // A: 64 rows x 4 segs of 16
  const int brow = tid >> 1, bhalf = tid & 1;  // B: 128 rows x 2 halves of 32

  for (int k0 = 0; k0 < K; k0 += BK) {
    // ---- stage A (64 x 64) ----
    {
      unsigned short tmp[16];
      if (A_BF16) {
        const unsigned short* Ab = (const unsigned short*)Ap;
        const uint4* src = (const uint4*)&Ab[(size_t)(m0 + arow) * K + k0 + aseg * 16];
        *(uint4*)&tmp[0] = src[0];
        *(uint4*)&tmp[8] = src[1];
      } else {
        const float* Af = (const float*)Ap;
        const float4* src = (const float4*)&Af[(size_t)(m0 + arow) * K + k0 + aseg * 16];
#pragma unroll
        for (int v = 0; v < 4; ++v) {
          float4 a4 = src[v];
          if (FUSE_ADD) {
            const float4 b4 = ((const float4*)&A2[(size_t)(m0 + arow) * K + k0 + aseg * 16])[v];
            a4.x += b4.x; a4.y += b4.y; a4.z += b4.z; a4.w += b4.w;
          }
          tmp[v * 4 + 0] = f2bf(a4.x);
          tmp[v * 4 + 1] = f2bf(a4.y);
          tmp[v * 4 + 2] = f2bf(a4.z);
          tmp[v * 4 + 3] = f2bf(a4.w);
        }
      }
      uint4* dst = (uint4*)&As[arow * LDA + aseg * 16];
      dst[0] = *(const uint4*)&tmp[0];
      dst[1] = *(const uint4*)&tmp[8];
    }
    // ---- stage B (128 x 64) from W[N,256] bf16, zero-fill n >= N ----
    {
      uint4 z = make_uint4(0, 0, 0, 0);
      uint4 t0 = z, t1 = z, t2 = z, t3 = z;
      if (n0 + brow < N) {
        const uint4* src = (const uint4*)&Wb[(size_t)(n0 + brow) * K + k0 + bhalf * 32];
        t0 = src[0]; t1 = src[1]; t2 = src[2]; t3 = src[3];
      }
      uint4* dst = (uint4*)&Bs[brow * LDA + bhalf * 32];
      dst[0] = t0; dst[1] = t1; dst[2] = t2; dst[3] = t3;
    }
    __syncthreads();

#pragma unroll
    for (int k32 = 0; k32 < 2; ++k32) {
      const int koff = k32 * 32 + quad * 8;
      short8 a[2], b[4];
#pragma unroll
      for (int mi = 0; mi < 2; ++mi)
        a[mi] = *(const short8*)&As[(wm * 32 + mi * 16 + l16) * LDA + koff];
#pragma unroll
      for (int ni = 0; ni < 4; ++ni)
        b[ni] = *(const short8*)&Bs[(wn * 64 + ni * 16 + l16) * LDA + koff];
#pragma unroll
      for (int mi = 0; mi < 2; ++mi)
#pragma unroll
        for (int ni = 0; ni < 4; ++ni)
          acc[mi][ni] = __builtin_amdgcn_mfma_f32_16x16x32_bf16(a[mi], b[ni], acc[mi][ni], 0, 0, 0);
    }
    __syncthreads();
  }

  // ---- epilogue ----
#pragma unroll
  for (int ni = 0; ni < 4; ++ni) {
    const int col = n0 + wn * 64 + ni * 16 + l16;
    if (col >= N) continue;
    const float bia = bias[col];
#pragma unroll
    for (int mi = 0; mi < 2; ++mi) {
      const int rbase = m0 + wm * 32 + mi * 16 + quad * 4;
#pragma unroll
      for (int r = 0; r < 4; ++r) {
        const float v = acc[mi][ni][r] + bia;
        if (OUT_BF16)
          ((unsigned short*)Cp)[(size_t)(rbase + r) * N + col] = f2bf(v);
        else
          ((float*)Cp)[(size_t)(rbase + r) * N + col] = v;
      }
    }
  }
}

// ---------------------------------------------------------------------------
// hs = bf16(hidden + pos), 8 elems/thread
// ---------------------------------------------------------------------------
__global__ __launch_bounds__(256) void cvt_add_kernel(
    const float* __restrict__ a, const float* __restrict__ b,
    unsigned short* __restrict__ o, int n8) {
  const int t = blockIdx.x * 256 + threadIdx.x;
  if (t >= n8) return;
  const float4* pa = (const float4*)(a + (size_t)t * 8);
  const float4* pb = (const float4*)(b + (size_t)t * 8);
  unsigned short tmp[8];
#pragma unroll
  for (int v = 0; v < 2; ++v) {
    float4 x = pa[v], y = pb[v];
    tmp[v * 4 + 0] = f2bf(x.x + y.x);
    tmp[v * 4 + 1] = f2bf(x.y + y.y);
    tmp[v * 4 + 2] = f2bf(x.z + y.z);
    tmp[v * 4 + 3] = f2bf(x.w + y.w);
  }
  *(uint4*)(o + (size_t)t * 8) = *(const uint4*)tmp;
}

// ---------------------------------------------------------------------------
// Convert the 4 weight matrices to bf16, packed: Wv | Ws | Wa | Wo
// sizes: 65536 | 49152 | 24576 | 65536  (total 204800), 4 elems/thread
// ---------------------------------------------------------------------------
__global__ __launch_bounds__(256) void cvt_weights_kernel(
    const float* __restrict__ Wv, const float* __restrict__ Ws,
    const float* __restrict__ Wa, const float* __restrict__ Wo,
    unsigned short* __restrict__ o) {
  const int t = blockIdx.x * 256 + threadIdx.x;
  const int e = t * 4;
  if (e >= 204800) return;
  const float* src;
  int off;
  if (e < 65536)       { src = Wv; off = e; }
  else if (e < 114688) { src = Ws; off = e - 65536; }
  else if (e < 139264) { src = Wa; off = e - 114688; }
  else                 { src = Wo; off = e - 139264; }
  float4 x = *(const float4*)(src + off);
  unsigned short tmp[4] = {f2bf(x.x), f2bf(x.y), f2bf(x.z), f2bf(x.w)};
  *(uint2*)(o + e) = *(const uint2*)tmp;
}

// ---------------------------------------------------------------------------
// In-place softmax over groups of 12 (one thread per (q, head)).
// ---------------------------------------------------------------------------
__global__ __launch_bounds__(256) void softmax12_kernel(float* __restrict__ x, int count) {
  const int t = blockIdx.x * blockDim.x + threadIdx.x;
  if (t >= count) return;
  float* p = x + (size_t)t * 12;
  float v[12];
  float m = -1e30f;
#pragma unroll
  for (int i = 0; i < 12; ++i) { v[i] = p[i]; m = fmaxf(m, v[i]); }
  float s = 0.f;
#pragma unroll
  for (int i = 0; i < 12; ++i) { v[i] = expf(v[i] - m); s += v[i]; }
  const float inv = 1.f / s;
#pragma unroll
  for (int i = 0; i < 12; ++i) p[i] = v[i] * inv;
}

// ---------------------------------------------------------------------------
// Sampling + aggregation. One wave per (q, head); value is bf16; out is bf16.
// ---------------------------------------------------------------------------
__global__ __launch_bounds__(256) void msda_sample_kernel(
    const unsigned short* __restrict__ value,  // [Q, 256] bf16
    const float* __restrict__ sp,              // [Q, 192] raw offsets
    const float* __restrict__ attn,            // [Q, 96]  softmaxed
    const float* __restrict__ refp,            // [Q, 3, 2]
    unsigned short* __restrict__ outp) {       // [Q, 256] bf16
  const int gwave = (blockIdx.x * 256 + threadIdx.x) >> 6;
  const int lane = threadIdx.x & 63;
  const int q = gwave >> 3;
  const int h = gwave & 7;
  const int ph = lane >> 5;
  const int c = lane & 31;

  const int lsz[3] = {160, 80, 40};
  const int lst[3] = {0, 25600, 32000};

  float acc = 0.f;
#pragma unroll
  for (int it = 0; it < 6; ++it) {
    const int pt = it * 2 + ph;  // 0..11
    const int lvl = pt >> 2;
    const float a  = attn[(size_t)q * 96 + h * 12 + pt];
    const float ox = sp[(size_t)q * 192 + h * 24 + pt * 2 + 0];
    const float oy = sp[(size_t)q * 192 + h * 24 + pt * 2 + 1];
    const float rx = refp[(size_t)q * 6 + lvl * 2 + 0];
    const float ry = refp[(size_t)q * 6 + lvl * 2 + 1];
    const int S = lsz[lvl];
    const int base = lst[lvl];

    const float x = rx * (float)S + ox - 0.5f;
    const float y = ry * (float)S + oy - 0.5f;
    const float xf = floorf(x), yf = floorf(y);
    const int x0 = (int)xf, y0 = (int)yf;
    const float wx1 = x - xf, wy1 = y - yf;
    const float wx0 = 1.f - wx1, wy0 = 1.f - wy1;

    const bool xv0 = (x0 >= 0) & (x0 < S);
    const bool xv1 = (x0 + 1 >= 0) & (x0 + 1 < S);
    const bool yv0 = (y0 >= 0) & (y0 < S);
    const bool yv1 = (y0 + 1 >= 0) & (y0 + 1 < S);

    float v00 = 0.f, v10 = 0.f, v01 = 0.f, v11 = 0.f;
    if (yv0) {
      const unsigned short* row = value + ((size_t)(base + y0 * S)) * 256 + h * 32 + c;
      if (xv0) v00 = bf2f(row[(size_t)x0 * 256]);
      if (xv1) v10 = bf2f(row[(size_t)(x0 + 1) * 256]);
    }
    if (yv1) {
      const unsigned short* row = value + ((size_t)(base + (y0 + 1) * S)) * 256 + h * 32 + c;
      if (xv0) v01 = bf2f(row[(size_t)x0 * 256]);
      if (xv1) v11 = bf2f(row[(size_t)(x0 + 1) * 256]);
    }
    acc += a * (v00 * wx0 * wy0 + v10 * wx1 * wy0 + v01 * wx0 * wy1 + v11 * wx1 * wy1);
  }
  acc += __shfl_down(acc, 32, 64);
  if (ph == 0) outp[(size_t)q * 256 + h * 32 + c] = f2bf(acc);
}

extern "C" void kernel_launch(void* const* d_in, const int* in_sizes, int n_in,
                              void* d_out, int out_size, void* d_ws, size_t ws_size,
                              hipStream_t stream) {
  const float* hidden = (const float*)d_in[0];
  const float* ehs    = (const float*)d_in[1];
  const float* pos    = (const float*)d_in[2];
  const float* refp   = (const float*)d_in[3];
  const float* Wv = (const float*)d_in[4];
  const float* bv = (const float*)d_in[5];
  const float* Ws = (const float*)d_in[6];
  const float* bs = (const float*)d_in[7];
  const float* Wa = (const float*)d_in[8];
  const float* ba = (const float*)d_in[9];
  const float* Wo = (const float*)d_in[10];
  const float* bo = (const float*)d_in[11];

  float* out  = (float*)d_out;             // [Q, 256]
  float* attn = out + (size_t)QSEQ * 256;  // [Q, 96]

  // workspace layout (bytes)
  char* ws = (char*)d_ws;
  unsigned short* ws_value = (unsigned short*)ws;                       // Q*256 bf16
  unsigned short* ws_hs    = ws_value + (size_t)QSEQ * 256;             // Q*256 bf16
  unsigned short* ws_outp  = ws_hs + (size_t)QSEQ * 256;                // Q*256 bf16
  unsigned short* ws_w     = ws_outp + (size_t)QSEQ * 256;              // 204800 bf16
  float* ws_sp = (float*)(ws_w + 204800);                               // Q*192 fp32

  unsigned short* Wv_b = ws_w;
  unsigned short* Ws_b = ws_w + 65536;
  unsigned short* Wa_b = ws_w + 114688;
  unsigned short* Wo_b = ws_w + 139264;

  dim3 blk(256);

  // 0. conversions
  cvt_weights_kernel<<<dim3(201), blk, 0, stream>>>(Wv, Ws, Wa, Wo, ws_w);
  cvt_add_kernel<<<dim3((QSEQ * 256 / 8 + 255) / 256), blk, 0, stream>>>(hidden, pos, ws_hs, QSEQ * 256 / 8);

  // 1. value = ehs @ Wv^T + bv  (fp32 A inline-cvt, bf16 out)
  gemm_mfma_kernel<false, true, false><<<dim3(2, 525), blk, 0, stream>>>(ehs, nullptr, Wv_b, bv, ws_value, 256);
  // 2. offsets = hs @ Ws^T + bs (bf16 A, fp32 out)
  gemm_mfma_kernel<true, false, false><<<dim3(2, 525), blk, 0, stream>>>(ws_hs, nullptr, Ws_b, bs, ws_sp, 192);
  // 3. attn logits = hs @ Wa^T + ba (bf16 A, fp32 out -> d_out attn region)
  gemm_mfma_kernel<true, false, false><<<dim3(1, 525), blk, 0, stream>>>(ws_hs, nullptr, Wa_b, ba, attn, 96);
  // 4. softmax
  softmax12_kernel<<<dim3((QSEQ * NHEADS + 255) / 256), blk, 0, stream>>>(attn, QSEQ * NHEADS);
  // 5. sampling
  msda_sample_kernel<<<dim3(QSEQ * NHEADS / 4), blk, 0, stream>>>(ws_value, ws_sp, attn, refp, ws_outp);
  // 6. output = sampled @ Wo^T + bo (bf16 A, fp32 out)
  gemm_mfma_kernel<true, false, false><<<dim3(2, 525), blk, 0, stream>>>(ws_outp, nullptr, Wo_b, bo, out, 256);
}

// Round 3
// 345.281 us; speedup vs baseline: 1.6910x; 1.6910x over previous
//
#include <hip/hip_runtime.h>
#include <math.h>

#define QSEQ 33600
#define DM 256
#define NHEADS 8

typedef __attribute__((ext_vector_type(8))) short short8;
typedef __attribute__((ext_vector_type(4))) float floatx4;

static __device__ __forceinline__ unsigned short f2bf(float f) {
  unsigned u = __float_as_uint(f);
  unsigned r = (u + 0x7FFF + ((u >> 16) & 1)) >> 16;
  return (unsigned short)r;
}

// ---------------------------------------------------------------------------
// MFMA GEMM: C[M,N] = A @ W^T + bias.
// A: [M,256] (fp32 inline-cvt or bf16), W: [N,256] bf16 (pre-cvt).
// BM=64, BN=128, BK=64, 256 threads = 4 waves, wave tile 32x64 (2x4 MFMA frags).
// OUT_HM: write bf16 head-major [col>>5][row][col&31] (for the sampler).
// ---------------------------------------------------------------------------
template <bool A_BF16, bool OUT_BF16, bool OUT_HM>
__global__ __launch_bounds__(256) void gemm_mfma_kernel(
    const void* __restrict__ Ap,
    const unsigned short* __restrict__ Wb, const float* __restrict__ bias,
    void* __restrict__ Cp, int N) {
  constexpr int K = 256, BK = 64, LDA = BK + 8;  // pad 8 elems (16B)
  __shared__ unsigned short As[64 * LDA];
  __shared__ unsigned short Bs[128 * LDA];

  const int tid = threadIdx.x;
  const int m0 = blockIdx.y * 64;
  const int n0 = blockIdx.x * 128;
  const int wave = tid >> 6, lane = tid & 63;
  const int wm = wave >> 1, wn = wave & 1;
  const int l16 = lane & 15, quad = lane >> 4;

  floatx4 acc[2][4];
#pragma unroll
  for (int i = 0; i < 2; ++i)
#pragma unroll
    for (int j = 0; j < 4; ++j) acc[i][j] = (floatx4)(0.f);

  const int arow = tid >> 2, aseg = tid & 3;   // A: 64 rows x 4 segs of 16
  const int brow = tid >> 1, bhalf = tid & 1;  // B: 128 rows x 2 halves of 32

  for (int k0 = 0; k0 < K; k0 += BK) {
    // ---- stage A (64 x 64) ----
    {
      unsigned short tmp[16];
      if (A_BF16) {
        const unsigned short* Ab = (const unsigned short*)Ap;
        const uint4* src = (const uint4*)&Ab[(size_t)(m0 + arow) * K + k0 + aseg * 16];
        *(uint4*)&tmp[0] = src[0];
        *(uint4*)&tmp[8] = src[1];
      } else {
        const float* Af = (const float*)Ap;
        const float4* src = (const float4*)&Af[(size_t)(m0 + arow) * K + k0 + aseg * 16];
#pragma unroll
        for (int v = 0; v < 4; ++v) {
          float4 a4 = src[v];
          tmp[v * 4 + 0] = f2bf(a4.x);
          tmp[v * 4 + 1] = f2bf(a4.y);
          tmp[v * 4 + 2] = f2bf(a4.z);
          tmp[v * 4 + 3] = f2bf(a4.w);
        }
      }
      uint4* dst = (uint4*)&As[arow * LDA + aseg * 16];
      dst[0] = *(const uint4*)&tmp[0];
      dst[1] = *(const uint4*)&tmp[8];
    }
    // ---- stage B (128 x 64) from W[N,256] bf16, zero-fill n >= N ----
    {
      uint4 z = make_uint4(0, 0, 0, 0);
      uint4 t0 = z, t1 = z, t2 = z, t3 = z;
      if (n0 + brow < N) {
        const uint4* src = (const uint4*)&Wb[(size_t)(n0 + brow) * K + k0 + bhalf * 32];
        t0 = src[0]; t1 = src[1]; t2 = src[2]; t3 = src[3];
      }
      uint4* dst = (uint4*)&Bs[brow * LDA + bhalf * 32];
      dst[0] = t0; dst[1] = t1; dst[2] = t2; dst[3] = t3;
    }
    __syncthreads();

#pragma unroll
    for (int k32 = 0; k32 < 2; ++k32) {
      const int koff = k32 * 32 + quad * 8;
      short8 a[2], b[4];
#pragma unroll
      for (int mi = 0; mi < 2; ++mi)
        a[mi] = *(const short8*)&As[(wm * 32 + mi * 16 + l16) * LDA + koff];
#pragma unroll
      for (int ni = 0; ni < 4; ++ni)
        b[ni] = *(const short8*)&Bs[(wn * 64 + ni * 16 + l16) * LDA + koff];
#pragma unroll
      for (int mi = 0; mi < 2; ++mi)
#pragma unroll
        for (int ni = 0; ni < 4; ++ni)
          acc[mi][ni] = __builtin_amdgcn_mfma_f32_16x16x32_bf16(a[mi], b[ni], acc[mi][ni], 0, 0, 0);
    }
    __syncthreads();
  }

  // ---- epilogue ----
#pragma unroll
  for (int ni = 0; ni < 4; ++ni) {
    const int col = n0 + wn * 64 + ni * 16 + l16;
    if (col >= N) continue;
    const float bia = bias[col];
#pragma unroll
    for (int mi = 0; mi < 2; ++mi) {
      const int rbase = m0 + wm * 32 + mi * 16 + quad * 4;
#pragma unroll
      for (int r = 0; r < 4; ++r) {
        const float v = acc[mi][ni][r] + bia;
        if (OUT_HM) {
          // head-major bf16: [col>>5][row][col&31]
          ((unsigned short*)Cp)[((size_t)(col >> 5) * QSEQ + (rbase + r)) * 32 + (col & 31)] = f2bf(v);
        } else if (OUT_BF16) {
          ((unsigned short*)Cp)[(size_t)(rbase + r) * N + col] = f2bf(v);
        } else {
          ((float*)Cp)[(size_t)(rbase + r) * N + col] = v;
        }
      }
    }
  }
}

// ---------------------------------------------------------------------------
// hs = bf16(hidden + pos), 8 elems/thread
// ---------------------------------------------------------------------------
__global__ __launch_bounds__(256) void cvt_add_kernel(
    const float* __restrict__ a, const float* __restrict__ b,
    unsigned short* __restrict__ o, int n8) {
  const int t = blockIdx.x * 256 + threadIdx.x;
  if (t >= n8) return;
  const float4* pa = (const float4*)(a + (size_t)t * 8);
  const float4* pb = (const float4*)(b + (size_t)t * 8);
  unsigned short tmp[8];
#pragma unroll
  for (int v = 0; v < 2; ++v) {
    float4 x = pa[v], y = pb[v];
    tmp[v * 4 + 0] = f2bf(x.x + y.x);
    tmp[v * 4 + 1] = f2bf(x.y + y.y);
    tmp[v * 4 + 2] = f2bf(x.z + y.z);
    tmp[v * 4 + 3] = f2bf(x.w + y.w);
  }
  *(uint4*)(o + (size_t)t * 8) = *(const uint4*)tmp;
}

// ---------------------------------------------------------------------------
// Convert the 4 weight matrices to bf16, packed: Wv | Ws | Wa | Wo
// ---------------------------------------------------------------------------
__global__ __launch_bounds__(256) void cvt_weights_kernel(
    const float* __restrict__ Wv, const float* __restrict__ Ws,
    const float* __restrict__ Wa, const float* __restrict__ Wo,
    unsigned short* __restrict__ o) {
  const int t = blockIdx.x * 256 + threadIdx.x;
  const int e = t * 4;
  if (e >= 204800) return;
  const float* src;
  int off;
  if (e < 65536)       { src = Wv; off = e; }
  else if (e < 114688) { src = Ws; off = e - 65536; }
  else if (e < 139264) { src = Wa; off = e - 114688; }
  else                 { src = Wo; off = e - 139264; }
  float4 x = *(const float4*)(src + off);
  unsigned short tmp[4] = {f2bf(x.x), f2bf(x.y), f2bf(x.z), f2bf(x.w)};
  *(uint2*)(o + e) = *(const uint2*)tmp;
}

// ---------------------------------------------------------------------------
// In-place softmax over groups of 12 (one thread per (q, head)).
// ---------------------------------------------------------------------------
__global__ __launch_bounds__(256) void softmax12_kernel(float* __restrict__ x, int count) {
  const int t = blockIdx.x * blockDim.x + threadIdx.x;
  if (t >= count) return;
  float* p = x + (size_t)t * 12;
  float v[12];
  float m = -1e30f;
#pragma unroll
  for (int i = 0; i < 12; ++i) { v[i] = p[i]; m = fmaxf(m, v[i]); }
  float s = 0.f;
#pragma unroll
  for (int i = 0; i < 12; ++i) { v[i] = expf(v[i] - m); s += v[i]; }
  const float inv = 1.f / s;
#pragma unroll
  for (int i = 0; i < 12; ++i) p[i] = v[i] * inv;
}

// ---------------------------------------------------------------------------
// Sampling + aggregation, point-parallel.
// One wave per (q, h). lane = cg*16 + pt: pt in [0,12) is the sampling point,
// cg in [0,4) is a group of 8 channels. Each tap = one 16B load (8 bf16 ch).
// value is head-major [8][QSEQ][32] so each head slice is 2.15 MB (fits L2),
// and h = blockIdx.x & 7 aligns heads with the round-robin block->XCD map.
// ---------------------------------------------------------------------------
static __device__ __forceinline__ void tap_acc(const unsigned short* p, float w, float* facc) {
  const uint4 u = *(const uint4*)p;
  const unsigned uu[4] = {u.x, u.y, u.z, u.w};
#pragma unroll
  for (int i = 0; i < 4; ++i) {
    const float lo = __uint_as_float(uu[i] << 16);
    const float hi = __uint_as_float(uu[i] & 0xFFFF0000u);
    facc[2 * i + 0] = fmaf(lo, w, facc[2 * i + 0]);
    facc[2 * i + 1] = fmaf(hi, w, facc[2 * i + 1]);
  }
}

__global__ __launch_bounds__(256) void msda_sample_kernel(
    const unsigned short* __restrict__ value,  // [8][QSEQ][32] bf16
    const float* __restrict__ sp,              // [Q, 192] raw offsets
    const float* __restrict__ attn,            // [Q, 96]  softmaxed
    const float* __restrict__ refp,            // [Q, 3, 2]
    unsigned short* __restrict__ outp) {       // [Q, 256] bf16
  const int h = blockIdx.x & 7;
  const int qblk = blockIdx.x >> 3;
  const int wave = threadIdx.x >> 6;
  const int lane = threadIdx.x & 63;
  const int q = qblk * 4 + wave;
  const int cg = lane >> 4;   // channel group (8 channels)
  const int pt = lane & 15;   // sampling point
  const bool active = pt < 12;
  const int ptc = active ? pt : 11;
  const int lvl = ptc >> 2;

  const int lsz[3] = {160, 80, 40};
  const int lst[3] = {0, 25600, 32000};
  const int S = lsz[lvl];
  const int base = lst[lvl];

  const float a = active ? attn[(size_t)q * 96 + h * 12 + ptc] : 0.f;
  const float2 off = *(const float2*)&sp[(size_t)q * 192 + h * 24 + ptc * 2];
  const float2 rp = *(const float2*)&refp[(size_t)q * 6 + lvl * 2];

  const float x = rp.x * (float)S + off.x - 0.5f;
  const float y = rp.y * (float)S + off.y - 0.5f;
  const float xf = floorf(x), yf = floorf(y);
  const int x0 = (int)xf, y0 = (int)yf;
  const float wx1 = x - xf, wy1 = y - yf;
  const float wx0 = 1.f - wx1, wy0 = 1.f - wy1;

  const bool xv0 = (x0 >= 0) & (x0 < S);
  const bool xv1 = (x0 >= -1) & (x0 < S - 1);
  const bool yv0 = (y0 >= 0) & (y0 < S);
  const bool yv1 = (y0 >= -1) & (y0 < S - 1);

  const float w00 = a * wx0 * wy0, w10 = a * wx1 * wy0;
  const float w01 = a * wx0 * wy1, w11 = a * wx1 * wy1;

  const long pix = (long)h * QSEQ + base + (long)y0 * S + x0;
  const unsigned short* vp = value + pix * 32 + cg * 8;

  float facc[8] = {0.f, 0.f, 0.f, 0.f, 0.f, 0.f, 0.f, 0.f};
  if (active) {
    if (xv0 & yv0) tap_acc(vp, w00, facc);
    if (xv1 & yv0) tap_acc(vp + 32, w10, facc);
    if (xv0 & yv1) tap_acc(vp + (size_t)S * 32, w01, facc);
    if (xv1 & yv1) tap_acc(vp + (size_t)S * 32 + 32, w11, facc);
  }

  // reduce over pt (16-lane groups; inactive lanes contribute 0)
#pragma unroll
  for (int m = 1; m < 16; m <<= 1)
#pragma unroll
    for (int i = 0; i < 8; ++i) facc[i] += __shfl_xor(facc[i], m, 64);

  if (pt == 0) {
    unsigned short t[8];
#pragma unroll
    for (int i = 0; i < 8; ++i) t[i] = f2bf(facc[i]);
    *(uint4*)&outp[(size_t)q * 256 + h * 32 + cg * 8] = *(const uint4*)t;
  }
}

extern "C" void kernel_launch(void* const* d_in, const int* in_sizes, int n_in,
                              void* d_out, int out_size, void* d_ws, size_t ws_size,
                              hipStream_t stream) {
  const float* hidden = (const float*)d_in[0];
  const float* ehs    = (const float*)d_in[1];
  const float* pos    = (const float*)d_in[2];
  const float* refp   = (const float*)d_in[3];
  const float* Wv = (const float*)d_in[4];
  const float* bv = (const float*)d_in[5];
  const float* Ws = (const float*)d_in[6];
  const float* bs = (const float*)d_in[7];
  const float* Wa = (const float*)d_in[8];
  const float* ba = (const float*)d_in[9];
  const float* Wo = (const float*)d_in[10];
  const float* bo = (const float*)d_in[11];

  float* out  = (float*)d_out;             // [Q, 256]
  float* attn = out + (size_t)QSEQ * 256;  // [Q, 96]

  char* ws = (char*)d_ws;
  unsigned short* ws_value = (unsigned short*)ws;            // [8][Q][32] bf16
  unsigned short* ws_hs    = ws_value + (size_t)QSEQ * 256;  // [Q,256] bf16
  unsigned short* ws_outp  = ws_hs + (size_t)QSEQ * 256;     // [Q,256] bf16
  unsigned short* ws_w     = ws_outp + (size_t)QSEQ * 256;   // 204800 bf16
  float* ws_sp = (float*)(ws_w + 204800);                    // [Q,192] fp32

  unsigned short* Wv_b = ws_w;
  unsigned short* Ws_b = ws_w + 65536;
  unsigned short* Wa_b = ws_w + 114688;
  unsigned short* Wo_b = ws_w + 139264;

  dim3 blk(256);

  // 0. conversions
  cvt_weights_kernel<<<dim3(201), blk, 0, stream>>>(Wv, Ws, Wa, Wo, ws_w);
  cvt_add_kernel<<<dim3((QSEQ * 256 / 8 + 255) / 256), blk, 0, stream>>>(hidden, pos, ws_hs, QSEQ * 256 / 8);

  // 1. value = ehs @ Wv^T + bv  (fp32 A inline-cvt, bf16 head-major out)
  gemm_mfma_kernel<false, true, true><<<dim3(2, 525), blk, 0, stream>>>(ehs, Wv_b, bv, ws_value, 256);
  // 2. offsets = hs @ Ws^T + bs (bf16 A, fp32 out)
  gemm_mfma_kernel<true, false, false><<<dim3(2, 525), blk, 0, stream>>>(ws_hs, Ws_b, bs, ws_sp, 192);
  // 3. attn logits = hs @ Wa^T + ba (bf16 A, fp32 out -> d_out attn region)
  gemm_mfma_kernel<true, false, false><<<dim3(1, 525), blk, 0, stream>>>(ws_hs, Wa_b, ba, attn, 96);
  // 4. softmax
  softmax12_kernel<<<dim3((QSEQ * NHEADS + 255) / 256), blk, 0, stream>>>(attn, QSEQ * NHEADS);
  // 5. sampling (point-parallel, head-affine blocks)
  msda_sample_kernel<<<dim3((QSEQ / 4) * 8), blk, 0, stream>>>(ws_value, ws_sp, attn, refp, ws_outp);
  // 6. output = sampled @ Wo^T + bo (bf16 A, fp32 out)
  gemm_mfma_kernel<true, false, false><<<dim3(2, 525), blk, 0, stream>>>(ws_outp, Wo_b, bo, out, 256);
}

// Round 4
// 326.965 us; speedup vs baseline: 1.7857x; 1.0560x over previous
//
#include <hip/hip_runtime.h>
#include <math.h>

#define QSEQ 33600
#define NHEADS 8

typedef __attribute__((ext_vector_type(8))) short short8;
typedef __attribute__((ext_vector_type(4))) float floatx4;
typedef unsigned short ushort_t;

static __device__ __forceinline__ ushort_t f2bf(float f) {
  unsigned u = __float_as_uint(f);
  return (ushort_t)((u + 0x7FFF + ((u >> 16) & 1)) >> 16);
}

// async global->LDS, 16B per lane; lds dest = wave-uniform base + lane*16
static __device__ __forceinline__ void gload_lds16(const void* g, void* l) {
  __builtin_amdgcn_global_load_lds((__attribute__((address_space(1))) void*)g,
                                   (__attribute__((address_space(3))) void*)l, 16, 0, 0);
}

// ---------------------------------------------------------------------------
// m97-style MFMA GEMM: C[M,N] = A @ W^T + bias, A bf16 [M,256], W bf16 [N,256].
// BM=64, BN=128, BK=64, 256 thr = 4 waves (2x2), wave tile 32x64 (2x4 frags).
// LDS: unpadded row-major [rows][8 chunks of 16B], chunk-XOR swizzled:
//   slot (row, s) holds global chunk s ^ (row&7)  -> ds_read_b128 2-way (free),
//   staging loads stay within one 128B row segment (coalesced).
// MODE 0: fp32 [M,N] out. MODE 1: bf16 head-major [col>>5][row][col&31].
// MODE 2: N=96 attn logits -> fused softmax over groups of 12 -> fp32 out.
// W buffer must be readable up to 128-row multiples (garbage OK, stores guarded).
// ---------------------------------------------------------------------------
template <int MODE>
__global__ __launch_bounds__(256) void gemm_mfma2(
    const ushort_t* __restrict__ A, const ushort_t* __restrict__ Wb,
    const float* __restrict__ bias, void* __restrict__ Cp, int N) {
  __shared__ ushort_t smem[12288];  // As 4096 (8KB) | Bs 8192 (16KB); reused by MODE 2
  ushort_t* As = smem;
  ushort_t* Bs = smem + 4096;

  const int tid = threadIdx.x;
  const int m0 = blockIdx.y * 64;
  const int n0 = blockIdx.x * 128;
  const int wv = tid >> 6, lane = tid & 63;
  const int wm = wv >> 1, wn = wv & 1;
  const int l16 = lane & 15, quad = lane >> 4;

  // --- staging descriptors (invariant over k) ---
  const int ca0 = wv * 128 + lane, ca1 = ca0 + 64;
  const int ar0 = ca0 >> 3, ar1 = ca1 >> 3;
  const int ak0 = ((ca0 & 7) ^ (ar0 & 7)) * 8;
  const int ak1 = ((ca1 & 7) ^ (ar1 & 7)) * 8;
  const ushort_t* gA0 = A + (size_t)(m0 + ar0) * 256 + ak0;
  const ushort_t* gA1 = A + (size_t)(m0 + ar1) * 256 + ak1;
  ushort_t* lA0 = As + (wv * 128) * 8;       // wave-uniform
  ushort_t* lA1 = As + (wv * 128 + 64) * 8;

  const ushort_t* gB[4];
  ushort_t* lB[4];
#pragma unroll
  for (int j = 0; j < 4; ++j) {
    const int cb = wv * 256 + j * 64 + lane;
    const int br = cb >> 3;
    const int bk = ((cb & 7) ^ (br & 7)) * 8;
    gB[j] = Wb + (size_t)(n0 + br) * 256 + bk;
    lB[j] = Bs + (wv * 256 + j * 64) * 8;
  }

  floatx4 acc[2][4];
#pragma unroll
  for (int i = 0; i < 2; ++i)
#pragma unroll
    for (int j = 0; j < 4; ++j) acc[i][j] = (floatx4)(0.f);

  const int ra0 = wm * 32 + l16, ra1 = ra0 + 16;
  const int rb0 = wn * 64 + l16;
  const int l8 = l16 & 7;  // all frag rows are +16*k, so row&7 == l16&7

  for (int k0 = 0; k0 < 256; k0 += 64) {
    gload_lds16(gA0 + k0, lA0);
    gload_lds16(gA1 + k0, lA1);
#pragma unroll
    for (int j = 0; j < 4; ++j) gload_lds16(gB[j] + k0, lB[j]);
    __syncthreads();
#pragma unroll
    for (int k32 = 0; k32 < 2; ++k32) {
      const int cx = ((k32 * 4 + quad) ^ l8) * 8;  // swizzled chunk offset (ushorts)
      short8 a[2], b[4];
      a[0] = *(const short8*)&As[ra0 * 64 + cx];
      a[1] = *(const short8*)&As[ra1 * 64 + cx];
#pragma unroll
      for (int j = 0; j < 4; ++j)
        b[j] = *(const short8*)&Bs[(rb0 + j * 16) * 64 + cx];
#pragma unroll
      for (int mi = 0; mi < 2; ++mi)
#pragma unroll
        for (int ni = 0; ni < 4; ++ni)
          acc[mi][ni] = __builtin_amdgcn_mfma_f32_16x16x32_bf16(a[mi], b[ni], acc[mi][ni], 0, 0, 0);
    }
    __syncthreads();
  }

  if (MODE == 0) {
    float* C = (float*)Cp;
#pragma unroll
    for (int ni = 0; ni < 4; ++ni) {
      const int col = n0 + wn * 64 + ni * 16 + l16;
      if (col < N) {
        const float bia = bias[col];
#pragma unroll
        for (int mi = 0; mi < 2; ++mi) {
          const int rr = m0 + wm * 32 + mi * 16 + quad * 4;
#pragma unroll
          for (int r = 0; r < 4; ++r)
            C[(size_t)(rr + r) * N + col] = acc[mi][ni][r] + bia;
        }
      }
    }
  } else if (MODE == 1) {
    ushort_t* C = (ushort_t*)Cp;
#pragma unroll
    for (int ni = 0; ni < 4; ++ni) {
      const int col = n0 + wn * 64 + ni * 16 + l16;
      const float bia = bias[col];
      const int h = col >> 5, ch = col & 31;
#pragma unroll
      for (int mi = 0; mi < 2; ++mi) {
        const int rr = m0 + wm * 32 + mi * 16 + quad * 4;
#pragma unroll
        for (int r = 0; r < 4; ++r)
          C[((size_t)h * QSEQ + rr + r) * 32 + ch] = f2bf(acc[mi][ni][r] + bia);
      }
    }
  } else {
    // MODE 2: stage 64x96 logits in LDS, softmax groups of 12, write fp32
    float* smf = (float*)smem;
#pragma unroll
    for (int ni = 0; ni < 4; ++ni) {
      const int col = wn * 64 + ni * 16 + l16;
      if (col < 96) {
        const float bia = bias[col];
#pragma unroll
        for (int mi = 0; mi < 2; ++mi) {
          const int lr = wm * 32 + mi * 16 + quad * 4;
#pragma unroll
          for (int r = 0; r < 4; ++r)
            smf[(lr + r) * 96 + col] = acc[mi][ni][r] + bia;
        }
      }
    }
    __syncthreads();
    float* C = (float*)Cp;
#pragma unroll
    for (int p = 0; p < 2; ++p) {
      const int pair = tid * 2 + p;  // 0..511 = 64 rows x 8 heads
      const int row = pair >> 3, hh = pair & 7;
      float v[12];
      float mx = -1e30f;
#pragma unroll
      for (int i = 0; i < 12; ++i) {
        v[i] = smf[row * 96 + hh * 12 + i];
        mx = fmaxf(mx, v[i]);
      }
      float s = 0.f;
#pragma unroll
      for (int i = 0; i < 12; ++i) {
        v[i] = __expf(v[i] - mx);
        s += v[i];
      }
      const float inv = 1.f / s;
      float4 o[3];
#pragma unroll
      for (int i = 0; i < 3; ++i) {
        o[i].x = v[i * 4 + 0] * inv;
        o[i].y = v[i * 4 + 1] * inv;
        o[i].z = v[i * 4 + 2] * inv;
        o[i].w = v[i * 4 + 3] * inv;
      }
      float4* dst = (float4*)&C[(size_t)(m0 + row) * 96 + hh * 12];
      dst[0] = o[0];
      dst[1] = o[1];
      dst[2] = o[2];
    }
  }
}

// ---------------------------------------------------------------------------
// hs = bf16(hidden + pos); ehsb = bf16(ehs). 8 elems/thread each.
// ---------------------------------------------------------------------------
__global__ __launch_bounds__(256) void cvt_add_kernel(
    const float* __restrict__ a, const float* __restrict__ b, const float* __restrict__ e,
    ushort_t* __restrict__ hs, ushort_t* __restrict__ eb, int n8) {
  const int t = blockIdx.x * 256 + threadIdx.x;
  if (t >= n8) return;
  const float4* pa = (const float4*)(a + (size_t)t * 8);
  const float4* pb = (const float4*)(b + (size_t)t * 8);
  const float4* pe = (const float4*)(e + (size_t)t * 8);
  ushort_t t1[8], t2[8];
#pragma unroll
  for (int v = 0; v < 2; ++v) {
    const float4 x = pa[v], y = pb[v], z = pe[v];
    t1[v * 4 + 0] = f2bf(x.x + y.x);
    t1[v * 4 + 1] = f2bf(x.y + y.y);
    t1[v * 4 + 2] = f2bf(x.z + y.z);
    t1[v * 4 + 3] = f2bf(x.w + y.w);
    t2[v * 4 + 0] = f2bf(z.x);
    t2[v * 4 + 1] = f2bf(z.y);
    t2[v * 4 + 2] = f2bf(z.z);
    t2[v * 4 + 3] = f2bf(z.w);
  }
  *(uint4*)(hs + (size_t)t * 8) = *(const uint4*)t1;
  *(uint4*)(eb + (size_t)t * 8) = *(const uint4*)t2;
}

// ---------------------------------------------------------------------------
// Convert the 4 weight matrices to bf16, packed: Wv | Ws | Wa | Wo
// ---------------------------------------------------------------------------
__global__ __launch_bounds__(256) void cvt_weights_kernel(
    const float* __restrict__ Wv, const float* __restrict__ Ws,
    const float* __restrict__ Wa, const float* __restrict__ Wo,
    ushort_t* __restrict__ o) {
  const int t = blockIdx.x * 256 + threadIdx.x;
  const int e = t * 4;
  if (e >= 204800) return;
  const float* src;
  int off;
  if (e < 65536)       { src = Wv; off = e; }
  else if (e < 114688) { src = Ws; off = e - 65536; }
  else if (e < 139264) { src = Wa; off = e - 114688; }
  else                 { src = Wo; off = e - 139264; }
  const float4 x = *(const float4*)(src + off);
  ushort_t tmp[4] = {f2bf(x.x), f2bf(x.y), f2bf(x.z), f2bf(x.w)};
  *(uint2*)(o + e) = *(const uint2*)tmp;
}

// ---------------------------------------------------------------------------
// Sampling + aggregation, point-parallel, straight-line predicated taps.
// One wave per (q, h). lane = cg*16 + pt. Taps always issued with clamped
// coords; OOB handled by zeroing the per-axis weights (cndmask, no branches).
// ---------------------------------------------------------------------------
__global__ __launch_bounds__(256) void msda_sample_kernel(
    const ushort_t* __restrict__ value,  // [8][QSEQ][32] bf16
    const float* __restrict__ sp,        // [Q, 192]
    const float* __restrict__ attn,      // [Q, 96]
    const float* __restrict__ refp,      // [Q, 3, 2]
    ushort_t* __restrict__ outp) {       // [Q, 256] bf16
  const int h = blockIdx.x & 7;
  const int q = (blockIdx.x >> 3) * 4 + (threadIdx.x >> 6);
  const int lane = threadIdx.x & 63;
  const int cg = lane >> 4, pt = lane & 15;
  const int ptc = pt < 12 ? pt : 11;
  const int lvl = ptc >> 2;
  const int S = lvl == 0 ? 160 : (lvl == 1 ? 80 : 40);
  const int base = lvl == 0 ? 0 : (lvl == 1 ? 25600 : 32000);

  float a = attn[q * 96 + h * 12 + ptc];
  a = pt < 12 ? a : 0.f;
  const float2 off = *(const float2*)&sp[q * 192 + h * 24 + ptc * 2];
  const float2 rp = *(const float2*)&refp[q * 6 + lvl * 2];

  const float x = fmaf(rp.x, (float)S, off.x) - 0.5f;
  const float y = fmaf(rp.y, (float)S, off.y) - 0.5f;
  const float xf = floorf(x), yf = floorf(y);
  const int x0 = (int)xf, y0 = (int)yf;
  const float wx1 = x - xf, wy1 = y - yf;

  const float wx0z = (x0 >= 0 && x0 < S) ? 1.f - wx1 : 0.f;
  const float wx1z = (x0 + 1 >= 0 && x0 + 1 < S) ? wx1 : 0.f;
  const float wy0z = (y0 >= 0 && y0 < S) ? 1.f - wy1 : 0.f;
  const float wy1z = (y0 + 1 >= 0 && y0 + 1 < S) ? wy1 : 0.f;

  const int x0c = min(max(x0, 0), S - 1);
  const int x1c = min(max(x0 + 1, 0), S - 1);
  const int y0c = min(max(y0, 0), S - 1);
  const int y1c = min(max(y0 + 1, 0), S - 1);

  const float w00 = a * wx0z * wy0z, w10 = a * wx1z * wy0z;
  const float w01 = a * wx0z * wy1z, w11 = a * wx1z * wy1z;

  const ushort_t* hb = value + ((h * QSEQ + base) << 5) + cg * 8;
  const int r0 = y0c * S, r1 = y1c * S;
  const uint4 u00 = *(const uint4*)(hb + ((r0 + x0c) << 5));
  const uint4 u10 = *(const uint4*)(hb + ((r0 + x1c) << 5));
  const uint4 u01 = *(const uint4*)(hb + ((r1 + x0c) << 5));
  const uint4 u11 = *(const uint4*)(hb + ((r1 + x1c) << 5));

  float facc[8];
  {
    const unsigned a0[4] = {u00.x, u00.y, u00.z, u00.w};
    const unsigned a1[4] = {u10.x, u10.y, u10.z, u10.w};
    const unsigned a2[4] = {u01.x, u01.y, u01.z, u01.w};
    const unsigned a3[4] = {u11.x, u11.y, u11.z, u11.w};
#pragma unroll
    for (int i = 0; i < 4; ++i) {
      float lo = __uint_as_float(a0[i] << 16) * w00;
      float hi = __uint_as_float(a0[i] & 0xFFFF0000u) * w00;
      lo = fmaf(__uint_as_float(a1[i] << 16), w10, lo);
      hi = fmaf(__uint_as_float(a1[i] & 0xFFFF0000u), w10, hi);
      lo = fmaf(__uint_as_float(a2[i] << 16), w01, lo);
      hi = fmaf(__uint_as_float(a2[i] & 0xFFFF0000u), w01, hi);
      lo = fmaf(__uint_as_float(a3[i] << 16), w11, lo);
      hi = fmaf(__uint_as_float(a3[i] & 0xFFFF0000u), w11, hi);
      facc[2 * i + 0] = lo;
      facc[2 * i + 1] = hi;
    }
  }

  // reduce over pt within 16-lane groups
#pragma unroll
  for (int m = 1; m < 16; m <<= 1)
#pragma unroll
    for (int i = 0; i < 8; ++i) facc[i] += __shfl_xor(facc[i], m, 64);

  if (pt == 0) {
    ushort_t t[8];
#pragma unroll
    for (int i = 0; i < 8; ++i) t[i] = f2bf(facc[i]);
    *(uint4*)&outp[(size_t)q * 256 + h * 32 + cg * 8] = *(const uint4*)t;
  }
}

extern "C" void kernel_launch(void* const* d_in, const int* in_sizes, int n_in,
                              void* d_out, int out_size, void* d_ws, size_t ws_size,
                              hipStream_t stream) {
  const float* hidden = (const float*)d_in[0];
  const float* ehs    = (const float*)d_in[1];
  const float* pos    = (const float*)d_in[2];
  const float* refp   = (const float*)d_in[3];
  const float* Wv = (const float*)d_in[4];
  const float* bv = (const float*)d_in[5];
  const float* Ws = (const float*)d_in[6];
  const float* bs = (const float*)d_in[7];
  const float* Wa = (const float*)d_in[8];
  const float* ba = (const float*)d_in[9];
  const float* Wo = (const float*)d_in[10];
  const float* bo = (const float*)d_in[11];

  float* out  = (float*)d_out;             // [Q, 256]
  float* attn = out + (size_t)QSEQ * 256;  // [Q, 96]

  char* ws = (char*)d_ws;
  ushort_t* ws_value = (ushort_t*)ws;                       // [8][Q][32] bf16
  ushort_t* ws_hs    = ws_value + (size_t)QSEQ * 256;       // [Q,256] bf16
  ushort_t* ws_outp  = ws_hs + (size_t)QSEQ * 256;          // [Q,256] bf16 (aliases ehs_bf16)
  ushort_t* ws_w     = ws_outp + (size_t)QSEQ * 256;        // 204800 bf16
  float* ws_sp = (float*)(ws_w + 204800);                   // [Q,192] fp32

  ushort_t* Wv_b = ws_w;
  ushort_t* Ws_b = ws_w + 65536;
  ushort_t* Wa_b = ws_w + 114688;
  ushort_t* Wo_b = ws_w + 139264;

  dim3 blk(256);

  // 0. conversions (ehs_bf16 shares storage with ws_outp; disjoint lifetimes)
  cvt_weights_kernel<<<dim3(200), blk, 0, stream>>>(Wv, Ws, Wa, Wo, ws_w);
  cvt_add_kernel<<<dim3(4200), blk, 0, stream>>>(hidden, pos, ehs, ws_hs, ws_outp, QSEQ * 256 / 8);

  // 1. value = ehs @ Wv^T + bv  -> bf16 head-major
  gemm_mfma2<1><<<dim3(2, 525), blk, 0, stream>>>(ws_outp, Wv_b, bv, ws_value, 256);
  // 2. offsets = hs @ Ws^T + bs -> fp32
  gemm_mfma2<0><<<dim3(2, 525), blk, 0, stream>>>(ws_hs, Ws_b, bs, ws_sp, 192);
  // 3. attn = softmax(hs @ Wa^T + ba)  (fused epilogue) -> fp32 d_out region
  gemm_mfma2<2><<<dim3(1, 525), blk, 0, stream>>>(ws_hs, Wa_b, ba, attn, 96);
  // 4. sampling (overwrites ws_outp; ehs_bf16 no longer needed)
  msda_sample_kernel<<<dim3((QSEQ / 4) * 8), blk, 0, stream>>>(ws_value, ws_sp, attn, refp, ws_outp);
  // 5. output = sampled @ Wo^T + bo -> fp32
  gemm_mfma2<0><<<dim3(2, 525), blk, 0, stream>>>(ws_outp, Wo_b, bo, out, 256);
}

// Round 5
// 312.048 us; speedup vs baseline: 1.8711x; 1.0478x over previous
//
#include <hip/hip_runtime.h>
#include <math.h>

#define QSEQ 33600
#define NHEADS 8

typedef __attribute__((ext_vector_type(8))) short short8;
typedef __attribute__((ext_vector_type(4))) float floatx4;
typedef unsigned short ushort_t;

static __device__ __forceinline__ ushort_t f2bf(float f) {
  unsigned u = __float_as_uint(f);
  return (ushort_t)((u + 0x7FFF + ((u >> 16) & 1)) >> 16);
}

// async global->LDS, 16B per lane; lds dest = wave-uniform base + lane*16
static __device__ __forceinline__ void gload_lds16(const void* g, void* l) {
  __builtin_amdgcn_global_load_lds((__attribute__((address_space(1))) void*)g,
                                   (__attribute__((address_space(3))) void*)l, 16, 0, 0);
}

// ---------------------------------------------------------------------------
// MFMA GEMM, BM=96 (33600 = 350*96 exact), BN=128, BK=64, K=256.
// 256 thr = 4 waves (2x2), wave tile 48x64 (3x4 frags of 16x16x32 bf16).
// LDS (dynamic): As 96x64 bf16 (12KB) | Bs 128x64 bf16 (16KB); chunk-XOR
// swizzle: slot (row,s) holds global 16B-chunk s^(row&7).
// ASRC: 0 = A bf16 via global_load_lds; 1 = A fp32 (VGPR cvt);
//       2 = A fp32 + A2 fp32 fused add (VGPR cvt).
// MODE: 0 = fp32 C[M,N]; 1 = bf16 head-major [col>>5][row][col&31];
//       2 = merged N=288: cols [0,96) attn logits -> fused softmax -> C1 fp32
//           [Q,96]; cols [96,288) -> C2 fp32 [Q,192] (+b2 bias).
// ---------------------------------------------------------------------------
template <int ASRC, int MODE>
__global__ __launch_bounds__(256) void gemm96(
    const void* __restrict__ A1, const float* __restrict__ A2,
    const ushort_t* __restrict__ Wb, const float* __restrict__ b1,
    const float* __restrict__ b2, void* __restrict__ C1,
    float* __restrict__ C2, int N) {
  extern __shared__ ushort_t smem[];
  ushort_t* As = smem;          // 6144 ushorts
  ushort_t* Bs = smem + 6144;   // 8192 ushorts

  const int tid = threadIdx.x;
  const int m0 = blockIdx.y * 96;
  const int n0 = blockIdx.x * 128;
  const int wv = tid >> 6, lane = tid & 63;
  const int wm = wv >> 1, wn = wv & 1;
  const int l16 = lane & 15, quad = lane >> 4;
  const int l8 = l16 & 7;

  // --- A staging descriptors: 768 chunks (96 rows x 8), 3 per thread ---
  const ushort_t* gAb[3];
  ushort_t* lAb[3];
  const float* gAf[3];
  const float* gAf2[3];
  ushort_t* lAf[3];
#pragma unroll
  for (int i = 0; i < 3; ++i) {
    const int c = tid + i * 256;
    const int row = c >> 3, s = c & 7;
    if (ASRC == 0) {
      const int gch = s ^ (row & 7);
      gAb[i] = (const ushort_t*)A1 + (size_t)(m0 + row) * 256 + gch * 8;
      lAb[i] = As + (wv * 64 + i * 256) * 8;  // wave-uniform base
    } else {
      gAf[i] = (const float*)A1 + (size_t)(m0 + row) * 256 + s * 8;
      if (ASRC == 2) gAf2[i] = A2 + (size_t)(m0 + row) * 256 + s * 8;
      lAf[i] = As + row * 64 + (s ^ (row & 7)) * 8;
    }
  }
  // --- B staging: 1024 chunks (128 rows x 8), 4 per thread ---
  const ushort_t* gB[4];
  ushort_t* lB[4];
#pragma unroll
  for (int j = 0; j < 4; ++j) {
    const int cb = wv * 256 + j * 64 + lane;
    const int br = cb >> 3;
    const int gch = (cb & 7) ^ (br & 7);
    gB[j] = Wb + (size_t)(n0 + br) * 256 + gch * 8;
    lB[j] = Bs + (wv * 256 + j * 64) * 8;
  }

  floatx4 acc[3][4];
#pragma unroll
  for (int i = 0; i < 3; ++i)
#pragma unroll
    for (int j = 0; j < 4; ++j) acc[i][j] = (floatx4)(0.f);

  for (int k0 = 0; k0 < 256; k0 += 64) {
    if (ASRC == 0) {
#pragma unroll
      for (int i = 0; i < 3; ++i) gload_lds16(gAb[i] + k0, lAb[i]);
    } else {
#pragma unroll
      for (int i = 0; i < 3; ++i) {
        const float4 x0 = *(const float4*)(gAf[i] + k0);
        const float4 x1 = *(const float4*)(gAf[i] + k0 + 4);
        float v[8] = {x0.x, x0.y, x0.z, x0.w, x1.x, x1.y, x1.z, x1.w};
        if (ASRC == 2) {
          const float4 y0 = *(const float4*)(gAf2[i] + k0);
          const float4 y1 = *(const float4*)(gAf2[i] + k0 + 4);
          v[0] += y0.x; v[1] += y0.y; v[2] += y0.z; v[3] += y0.w;
          v[4] += y1.x; v[5] += y1.y; v[6] += y1.z; v[7] += y1.w;
        }
        ushort_t t[8];
#pragma unroll
        for (int e = 0; e < 8; ++e) t[e] = f2bf(v[e]);
        *(short8*)lAf[i] = *(const short8*)t;
      }
    }
#pragma unroll
    for (int j = 0; j < 4; ++j) gload_lds16(gB[j] + k0, lB[j]);
    __syncthreads();

#pragma unroll
    for (int k32 = 0; k32 < 2; ++k32) {
      const int cx = ((k32 * 4 + quad) ^ l8) * 8;
      short8 a[3], b[4];
#pragma unroll
      for (int mi = 0; mi < 3; ++mi)
        a[mi] = *(const short8*)&As[(wm * 48 + mi * 16 + l16) * 64 + cx];
#pragma unroll
      for (int ni = 0; ni < 4; ++ni)
        b[ni] = *(const short8*)&Bs[(wn * 64 + ni * 16 + l16) * 64 + cx];
#pragma unroll
      for (int mi = 0; mi < 3; ++mi)
#pragma unroll
        for (int ni = 0; ni < 4; ++ni)
          acc[mi][ni] = __builtin_amdgcn_mfma_f32_16x16x32_bf16(a[mi], b[ni], acc[mi][ni], 0, 0, 0);
    }
    __syncthreads();
  }

  if (MODE == 0) {
    float* C = (float*)C1;
#pragma unroll
    for (int ni = 0; ni < 4; ++ni) {
      const int col = n0 + wn * 64 + ni * 16 + l16;
      const float bia = b1[col];
#pragma unroll
      for (int mi = 0; mi < 3; ++mi) {
        const int rr = m0 + wm * 48 + mi * 16 + quad * 4;
#pragma unroll
        for (int r = 0; r < 4; ++r)
          C[(size_t)(rr + r) * N + col] = acc[mi][ni][r] + bia;
      }
    }
  } else if (MODE == 1) {
    ushort_t* C = (ushort_t*)C1;
#pragma unroll
    for (int ni = 0; ni < 4; ++ni) {
      const int col = n0 + wn * 64 + ni * 16 + l16;
      const float bia = b1[col];
      const int h = col >> 5, ch = col & 31;
#pragma unroll
      for (int mi = 0; mi < 3; ++mi) {
        const int rr = m0 + wm * 48 + mi * 16 + quad * 4;
#pragma unroll
        for (int r = 0; r < 4; ++r)
          C[((size_t)h * QSEQ + rr + r) * 32 + ch] = f2bf(acc[mi][ni][r] + bia);
      }
    }
  } else {
    // MODE 2: cols [0,96) -> logits to LDS (block x==0 only has them);
    //         cols [96,288) -> sp fp32 [Q,192]
    float* smf = (float*)smem;  // 96 x 96 fp32 (36 KB), reuses As/Bs
#pragma unroll
    for (int ni = 0; ni < 4; ++ni) {
      const int col = n0 + wn * 64 + ni * 16 + l16;
      if (col < 96) {
        const float bia = b1[col];
#pragma unroll
        for (int mi = 0; mi < 3; ++mi) {
          const int lr = wm * 48 + mi * 16 + quad * 4;
#pragma unroll
          for (int r = 0; r < 4; ++r)
            smf[(lr + r) * 96 + col] = acc[mi][ni][r] + bia;
        }
      } else if (col < 288) {
        const float bia = b2[col - 96];
#pragma unroll
        for (int mi = 0; mi < 3; ++mi) {
          const int rr = m0 + wm * 48 + mi * 16 + quad * 4;
#pragma unroll
          for (int r = 0; r < 4; ++r)
            C2[(size_t)(rr + r) * 192 + (col - 96)] = acc[mi][ni][r] + bia;
        }
      }
    }
    __syncthreads();
    if (blockIdx.x == 0) {
      float* C = (float*)C1;
#pragma unroll
      for (int p = 0; p < 3; ++p) {
        const int task = tid + p * 256;  // 768 = 96 rows x 8 heads
        const int row = task >> 3, hh = task & 7;
        float v[12];
        float mx = -1e30f;
#pragma unroll
        for (int i = 0; i < 12; ++i) {
          v[i] = smf[row * 96 + hh * 12 + i];
          mx = fmaxf(mx, v[i]);
        }
        float s = 0.f;
#pragma unroll
        for (int i = 0; i < 12; ++i) {
          v[i] = __expf(v[i] - mx);
          s += v[i];
        }
        const float inv = 1.f / s;
        float4 o[3];
#pragma unroll
        for (int i = 0; i < 3; ++i) {
          o[i].x = v[i * 4 + 0] * inv;
          o[i].y = v[i * 4 + 1] * inv;
          o[i].z = v[i * 4 + 2] * inv;
          o[i].w = v[i * 4 + 3] * inv;
        }
        float4* dst = (float4*)&C[(size_t)(m0 + row) * 96 + hh * 12];
        dst[0] = o[0];
        dst[1] = o[1];
        dst[2] = o[2];
      }
    }
  }
}

// ---------------------------------------------------------------------------
// Convert weights to bf16, packed: Wv | Wa | Ws | Wo (Wa before Ws so the
// merged [Wa;Ws] N=288 matrix is contiguous with attn cols first).
// sizes: 65536 | 24576 | 49152 | 65536 = 204800, 4 elems/thread.
// ---------------------------------------------------------------------------
__global__ __launch_bounds__(256) void cvt_weights_kernel(
    const float* __restrict__ Wv, const float* __restrict__ Ws,
    const float* __restrict__ Wa, const float* __restrict__ Wo,
    ushort_t* __restrict__ o) {
  const int t = blockIdx.x * 256 + threadIdx.x;
  const int e = t * 4;
  if (e >= 204800) return;
  const float* src;
  int off;
  if (e < 65536)       { src = Wv; off = e; }
  else if (e < 90112)  { src = Wa; off = e - 65536; }
  else if (e < 139264) { src = Ws; off = e - 90112; }
  else                 { src = Wo; off = e - 139264; }
  const float4 x = *(const float4*)(src + off);
  ushort_t tmp[4] = {f2bf(x.x), f2bf(x.y), f2bf(x.z), f2bf(x.w)};
  *(uint2*)(o + e) = *(const uint2*)tmp;
}

// ---------------------------------------------------------------------------
// Sampling + aggregation (unchanged from round 4).
// ---------------------------------------------------------------------------
__global__ __launch_bounds__(256) void msda_sample_kernel(
    const ushort_t* __restrict__ value,  // [8][QSEQ][32] bf16
    const float* __restrict__ sp,        // [Q, 192]
    const float* __restrict__ attn,      // [Q, 96]
    const float* __restrict__ refp,      // [Q, 3, 2]
    ushort_t* __restrict__ outp) {       // [Q, 256] bf16
  const int h = blockIdx.x & 7;
  const int q = (blockIdx.x >> 3) * 4 + (threadIdx.x >> 6);
  const int lane = threadIdx.x & 63;
  const int cg = lane >> 4, pt = lane & 15;
  const int ptc = pt < 12 ? pt : 11;
  const int lvl = ptc >> 2;
  const int S = lvl == 0 ? 160 : (lvl == 1 ? 80 : 40);
  const int base = lvl == 0 ? 0 : (lvl == 1 ? 25600 : 32000);

  float a = attn[q * 96 + h * 12 + ptc];
  a = pt < 12 ? a : 0.f;
  const float2 off = *(const float2*)&sp[q * 192 + h * 24 + ptc * 2];
  const float2 rp = *(const float2*)&refp[q * 6 + lvl * 2];

  const float x = fmaf(rp.x, (float)S, off.x) - 0.5f;
  const float y = fmaf(rp.y, (float)S, off.y) - 0.5f;
  const float xf = floorf(x), yf = floorf(y);
  const int x0 = (int)xf, y0 = (int)yf;
  const float wx1 = x - xf, wy1 = y - yf;

  const float wx0z = (x0 >= 0 && x0 < S) ? 1.f - wx1 : 0.f;
  const float wx1z = (x0 + 1 >= 0 && x0 + 1 < S) ? wx1 : 0.f;
  const float wy0z = (y0 >= 0 && y0 < S) ? 1.f - wy1 : 0.f;
  const float wy1z = (y0 + 1 >= 0 && y0 + 1 < S) ? wy1 : 0.f;

  const int x0c = min(max(x0, 0), S - 1);
  const int x1c = min(max(x0 + 1, 0), S - 1);
  const int y0c = min(max(y0, 0), S - 1);
  const int y1c = min(max(y0 + 1, 0), S - 1);

  const float w00 = a * wx0z * wy0z, w10 = a * wx1z * wy0z;
  const float w01 = a * wx0z * wy1z, w11 = a * wx1z * wy1z;

  const ushort_t* hb = value + ((h * QSEQ + base) << 5) + cg * 8;
  const int r0 = y0c * S, r1 = y1c * S;
  const uint4 u00 = *(const uint4*)(hb + ((r0 + x0c) << 5));
  const uint4 u10 = *(const uint4*)(hb + ((r0 + x1c) << 5));
  const uint4 u01 = *(const uint4*)(hb + ((r1 + x0c) << 5));
  const uint4 u11 = *(const uint4*)(hb + ((r1 + x1c) << 5));

  float facc[8];
  {
    const unsigned a0[4] = {u00.x, u00.y, u00.z, u00.w};
    const unsigned a1[4] = {u10.x, u10.y, u10.z, u10.w};
    const unsigned a2[4] = {u01.x, u01.y, u01.z, u01.w};
    const unsigned a3[4] = {u11.x, u11.y, u11.z, u11.w};
#pragma unroll
    for (int i = 0; i < 4; ++i) {
      float lo = __uint_as_float(a0[i] << 16) * w00;
      float hi = __uint_as_float(a0[i] & 0xFFFF0000u) * w00;
      lo = fmaf(__uint_as_float(a1[i] << 16), w10, lo);
      hi = fmaf(__uint_as_float(a1[i] & 0xFFFF0000u), w10, hi);
      lo = fmaf(__uint_as_float(a2[i] << 16), w01, lo);
      hi = fmaf(__uint_as_float(a2[i] & 0xFFFF0000u), w01, hi);
      lo = fmaf(__uint_as_float(a3[i] << 16), w11, lo);
      hi = fmaf(__uint_as_float(a3[i] & 0xFFFF0000u), w11, hi);
      facc[2 * i + 0] = lo;
      facc[2 * i + 1] = hi;
    }
  }

#pragma unroll
  for (int m = 1; m < 16; m <<= 1)
#pragma unroll
    for (int i = 0; i < 8; ++i) facc[i] += __shfl_xor(facc[i], m, 64);

  if (pt == 0) {
    ushort_t t[8];
#pragma unroll
    for (int i = 0; i < 8; ++i) t[i] = f2bf(facc[i]);
    *(uint4*)&outp[(size_t)q * 256 + h * 32 + cg * 8] = *(const uint4*)t;
  }
}

extern "C" void kernel_launch(void* const* d_in, const int* in_sizes, int n_in,
                              void* d_out, int out_size, void* d_ws, size_t ws_size,
                              hipStream_t stream) {
  const float* hidden = (const float*)d_in[0];
  const float* ehs    = (const float*)d_in[1];
  const float* pos    = (const float*)d_in[2];
  const float* refp   = (const float*)d_in[3];
  const float* Wv = (const float*)d_in[4];
  const float* bv = (const float*)d_in[5];
  const float* Ws = (const float*)d_in[6];
  const float* bs = (const float*)d_in[7];
  const float* Wa = (const float*)d_in[8];
  const float* ba = (const float*)d_in[9];
  const float* Wo = (const float*)d_in[10];
  const float* bo = (const float*)d_in[11];

  float* out  = (float*)d_out;             // [Q, 256]
  float* attn = out + (size_t)QSEQ * 256;  // [Q, 96]

  char* ws = (char*)d_ws;
  ushort_t* ws_value = (ushort_t*)ws;                  // [8][Q][32] bf16
  ushort_t* ws_outp  = ws_value + (size_t)QSEQ * 256;  // [Q,256] bf16 sampled
  ushort_t* ws_w     = ws_outp + (size_t)QSEQ * 256;   // 204800 bf16 weights
  float* ws_sp = (float*)(ws_w + 204800);              // [Q,192] fp32

  ushort_t* Wv_b = ws_w;            // [256,256]
  ushort_t* Wm_b = ws_w + 65536;    // merged [288,256] = [Wa(96); Ws(192)]
  ushort_t* Wo_b = ws_w + 139264;   // [256,256]

  dim3 blk(256);

  // 0. weight conversion (only non-fused prep left)
  cvt_weights_kernel<<<dim3(200), blk, 0, stream>>>(Wv, Ws, Wa, Wo, ws_w);

  // 1. value = bf16(ehs) @ Wv^T + bv -> bf16 head-major  (fused fp32 cvt)
  gemm96<1, 1><<<dim3(2, 350), blk, 28672, stream>>>(ehs, nullptr, Wv_b, bv, nullptr, ws_value, nullptr, 256);
  // 2. merged: hs=(hidden+pos) @ [Wa;Ws]^T: attn=softmax(cols<96) -> d_out,
  //    sp = cols[96,288) -> ws_sp  (fused add+cvt in staging)
  gemm96<2, 2><<<dim3(3, 350), blk, 36864, stream>>>(hidden, pos, Wm_b, ba, bs, attn, ws_sp, 288);
  // 3. sampling
  msda_sample_kernel<<<dim3((QSEQ / 4) * 8), blk, 0, stream>>>(ws_value, ws_sp, attn, refp, ws_outp);
  // 4. output = sampled @ Wo^T + bo -> fp32
  gemm96<0, 0><<<dim3(2, 350), blk, 28672, stream>>>(ws_outp, nullptr, Wo_b, bo, nullptr, out, nullptr, 256);
}

// Round 6
// 299.541 us; speedup vs baseline: 1.9492x; 1.0418x over previous
//
#include <hip/hip_runtime.h>
#include <math.h>

#define QSEQ 33600

typedef __attribute__((ext_vector_type(8))) short short8;
typedef __attribute__((ext_vector_type(4))) float floatx4;
typedef unsigned short ushort_t;

static __device__ __forceinline__ ushort_t f2bf(float f) {
  unsigned u = __float_as_uint(f);
  return (ushort_t)((u + 0x7FFF + ((u >> 16) & 1)) >> 16);
}

// async global->LDS, 16B per lane; lds dest = wave-uniform base + lane*16
static __device__ __forceinline__ void gload_lds16(const void* g, void* l) {
  __builtin_amdgcn_global_load_lds((__attribute__((address_space(1))) void*)g,
                                   (__attribute__((address_space(3))) void*)l, 16, 0, 0);
}

// ---------------------------------------------------------------------------
// MFMA GEMM body, BM=96 (33600 = 350*96), BN=128, BK=64, K=256.
// 256 thr = 4 waves (2x2), wave tile 48x64 (3x4 frags of 16x16x32 bf16).
// LDS: As 96x64 bf16 | Bs 128x64 bf16, chunk-XOR swizzle (slot (row,s) holds
// global 16B-chunk s^(row&7)).
// B is staged from *fp32* weights with inline bf16 convert (no pre-pass).
// B row select: global row < bsplit -> B1[row], else B2[row-bsplit] (clamped).
// ASRC: 0 = A bf16 via global_load_lds; 1 = A fp32 cvt; 2 = fp32 A1+A2 add.
// MODE: 0 = fp32 C1[M,N]; 1 = bf16 head-major [col>>5][row][col&31];
//       2 = N=288 merged: cols<96 logits -> fused softmax -> C1 [Q,96] fp32,
//           cols [96,288) -> C2 [Q,192] fp32 (+b2).
// ---------------------------------------------------------------------------
template <int ASRC, int MODE>
static __device__ __forceinline__ void gemm_body(
    const int bx, const int by,
    const float* __restrict__ A1, const float* __restrict__ A2,
    const ushort_t* __restrict__ Ab,
    const float* __restrict__ B1, const float* __restrict__ B2, const int bsplit,
    const float* __restrict__ b1, const float* __restrict__ b2,
    void* __restrict__ C1, float* __restrict__ C2, const int N,
    ushort_t* smem) {
  ushort_t* As = smem;         // 6144 ushorts
  ushort_t* Bs = smem + 6144;  // 8192 ushorts

  const int tid = threadIdx.x;
  const int m0 = by * 96;
  const int n0 = bx * 128;
  const int wv = tid >> 6, lane = tid & 63;
  const int wm = wv >> 1, wn = wv & 1;
  const int l16 = lane & 15, quad = lane >> 4;
  const int l8 = l16 & 7;

  // --- A staging descriptors: 768 chunks (96 rows x 8), 3 per thread ---
  const float* gAf[3];
  const float* gAf2[3];
  const ushort_t* gAb[3];
  ushort_t* lA[3];
#pragma unroll
  for (int i = 0; i < 3; ++i) {
    const int c = tid + i * 256;
    const int row = c >> 3, s = c & 7;
    if (ASRC == 0) {
      gAb[i] = Ab + (size_t)(m0 + row) * 256 + ((s ^ (row & 7)) * 8);
      lA[i] = As + (wv * 64 + i * 256) * 8;  // wave-uniform base, lane-linear
    } else {
      gAf[i] = A1 + (size_t)(m0 + row) * 256 + s * 8;
      if (ASRC == 2) gAf2[i] = A2 + (size_t)(m0 + row) * 256 + s * 8;
      lA[i] = As + row * 64 + (s ^ (row & 7)) * 8;
    }
  }
  // --- B staging: 1024 chunks (128 rows x 8), 4 per thread, fp32 src ---
  const float* gBf[4];
  ushort_t* lBf[4];
#pragma unroll
  for (int j = 0; j < 4; ++j) {
    const int c = tid + j * 256;
    const int row = c >> 3, s = c & 7;
    const int grow = n0 + row;
    const float* bsrc;
    int r2;
    if (grow < bsplit) {
      bsrc = B1;
      r2 = grow;
    } else {
      bsrc = B2;
      r2 = grow - bsplit;
      const int rmax = N - bsplit - 1;
      if (r2 > rmax) r2 = rmax;  // clamp: garbage cols, stores guarded
    }
    gBf[j] = bsrc + (size_t)r2 * 256 + s * 8;
    lBf[j] = Bs + row * 64 + (s ^ (row & 7)) * 8;
  }

  floatx4 acc[3][4];
#pragma unroll
  for (int i = 0; i < 3; ++i)
#pragma unroll
    for (int j = 0; j < 4; ++j) acc[i][j] = (floatx4)(0.f);

  for (int k0 = 0; k0 < 256; k0 += 64) {
    // ---- stage A ----
    if (ASRC == 0) {
#pragma unroll
      for (int i = 0; i < 3; ++i) gload_lds16(gAb[i] + k0, lA[i]);
    } else {
#pragma unroll
      for (int i = 0; i < 3; ++i) {
        const float4 x0 = *(const float4*)(gAf[i] + k0);
        const float4 x1 = *(const float4*)(gAf[i] + k0 + 4);
        float v[8] = {x0.x, x0.y, x0.z, x0.w, x1.x, x1.y, x1.z, x1.w};
        if (ASRC == 2) {
          const float4 y0 = *(const float4*)(gAf2[i] + k0);
          const float4 y1 = *(const float4*)(gAf2[i] + k0 + 4);
          v[0] += y0.x; v[1] += y0.y; v[2] += y0.z; v[3] += y0.w;
          v[4] += y1.x; v[5] += y1.y; v[6] += y1.z; v[7] += y1.w;
        }
        ushort_t t[8];
#pragma unroll
        for (int e = 0; e < 8; ++e) t[e] = f2bf(v[e]);
        *(short8*)lA[i] = *(const short8*)t;
      }
    }
    // ---- stage B (fp32 -> bf16 inline) ----
#pragma unroll
    for (int j = 0; j < 4; ++j) {
      const float4 x0 = *(const float4*)(gBf[j] + k0);
      const float4 x1 = *(const float4*)(gBf[j] + k0 + 4);
      ushort_t t[8] = {f2bf(x0.x), f2bf(x0.y), f2bf(x0.z), f2bf(x0.w),
                       f2bf(x1.x), f2bf(x1.y), f2bf(x1.z), f2bf(x1.w)};
      *(short8*)lBf[j] = *(const short8*)t;
    }
    __syncthreads();

#pragma unroll
    for (int k32 = 0; k32 < 2; ++k32) {
      const int cx = ((k32 * 4 + quad) ^ l8) * 8;
      short8 a[3], b[4];
#pragma unroll
      for (int mi = 0; mi < 3; ++mi)
        a[mi] = *(const short8*)&As[(wm * 48 + mi * 16 + l16) * 64 + cx];
#pragma unroll
      for (int ni = 0; ni < 4; ++ni)
        b[ni] = *(const short8*)&Bs[(wn * 64 + ni * 16 + l16) * 64 + cx];
#pragma unroll
      for (int mi = 0; mi < 3; ++mi)
#pragma unroll
        for (int ni = 0; ni < 4; ++ni)
          acc[mi][ni] = __builtin_amdgcn_mfma_f32_16x16x32_bf16(a[mi], b[ni], acc[mi][ni], 0, 0, 0);
    }
    __syncthreads();
  }

  if (MODE == 0) {
    float* C = (float*)C1;
#pragma unroll
    for (int ni = 0; ni < 4; ++ni) {
      const int col = n0 + wn * 64 + ni * 16 + l16;
      const float bia = b1[col];
#pragma unroll
      for (int mi = 0; mi < 3; ++mi) {
        const int rr = m0 + wm * 48 + mi * 16 + quad * 4;
#pragma unroll
        for (int r = 0; r < 4; ++r)
          C[(size_t)(rr + r) * N + col] = acc[mi][ni][r] + bia;
      }
    }
  } else if (MODE == 1) {
    ushort_t* C = (ushort_t*)C1;
#pragma unroll
    for (int ni = 0; ni < 4; ++ni) {
      const int col = n0 + wn * 64 + ni * 16 + l16;
      const float bia = b1[col];
      const int h = col >> 5, ch = col & 31;
#pragma unroll
      for (int mi = 0; mi < 3; ++mi) {
        const int rr = m0 + wm * 48 + mi * 16 + quad * 4;
#pragma unroll
        for (int r = 0; r < 4; ++r)
          C[((size_t)h * QSEQ + rr + r) * 32 + ch] = f2bf(acc[mi][ni][r] + bia);
      }
    }
  } else {
    // MODE 2: cols [0,96) -> LDS logits (only bx==0 has them), then softmax;
    //         cols [96,288) -> C2 fp32 [Q,192]
    float* smf = (float*)smem;  // 96x96 fp32, reuses As/Bs
#pragma unroll
    for (int ni = 0; ni < 4; ++ni) {
      const int col = n0 + wn * 64 + ni * 16 + l16;
      if (col < 96) {
        const float bia = b1[col];
#pragma unroll
        for (int mi = 0; mi < 3; ++mi) {
          const int lr = wm * 48 + mi * 16 + quad * 4;
#pragma unroll
          for (int r = 0; r < 4; ++r)
            smf[(lr + r) * 96 + col] = acc[mi][ni][r] + bia;
        }
      } else if (col < 288) {
        const float bia = b2[col - 96];
#pragma unroll
        for (int mi = 0; mi < 3; ++mi) {
          const int rr = m0 + wm * 48 + mi * 16 + quad * 4;
#pragma unroll
          for (int r = 0; r < 4; ++r)
            C2[(size_t)(rr + r) * 192 + (col - 96)] = acc[mi][ni][r] + bia;
        }
      }
    }
    __syncthreads();
    if (bx == 0) {
      float* C = (float*)C1;
#pragma unroll
      for (int p = 0; p < 3; ++p) {
        const int task = tid + p * 256;  // 768 = 96 rows x 8 heads
        const int row = task >> 3, hh = task & 7;
        float v[12];
        float mx = -1e30f;
#pragma unroll
        for (int i = 0; i < 12; ++i) {
          v[i] = smf[row * 96 + hh * 12 + i];
          mx = fmaxf(mx, v[i]);
        }
        float s = 0.f;
#pragma unroll
        for (int i = 0; i < 12; ++i) {
          v[i] = __expf(v[i] - mx);
          s += v[i];
        }
        const float inv = 1.f / s;
        float4 o[3];
#pragma unroll
        for (int i = 0; i < 3; ++i) {
          o[i].x = v[i * 4 + 0] * inv;
          o[i].y = v[i * 4 + 1] * inv;
          o[i].z = v[i * 4 + 2] * inv;
          o[i].w = v[i * 4 + 3] * inv;
        }
        float4* dst = (float4*)&C[(size_t)(m0 + row) * 96 + hh * 12];
        dst[0] = o[0];
        dst[1] = o[1];
        dst[2] = o[2];
      }
    }
  }
}

// ---------------------------------------------------------------------------
// ONE dispatch for both independent pre-sampler GEMMs: grid (5, 350).
// x in [0,2): value = bf16(ehs) @ Wv^T + bv -> head-major bf16
// x in [2,5): merged hs=(hidden+pos) @ [Wa;Ws]^T -> softmax attn + sp
// ---------------------------------------------------------------------------
__global__ __launch_bounds__(256) void pre_gemms(
    const float* __restrict__ ehs, const float* __restrict__ hidden,
    const float* __restrict__ pos,
    const float* __restrict__ Wv, const float* __restrict__ bv,
    const float* __restrict__ Wa, const float* __restrict__ ba,
    const float* __restrict__ Ws, const float* __restrict__ bs,
    ushort_t* __restrict__ value, float* __restrict__ attn,
    float* __restrict__ sp) {
  extern __shared__ ushort_t smem[];
  if (blockIdx.x < 2)
    gemm_body<1, 1>(blockIdx.x, blockIdx.y, ehs, nullptr, nullptr,
                    Wv, Wv, 1 << 30, bv, nullptr, value, nullptr, 256, smem);
  else
    gemm_body<2, 2>(blockIdx.x - 2, blockIdx.y, hidden, pos, nullptr,
                    Wa, Ws, 96, ba, bs, attn, sp, 288, smem);
}

// ---------------------------------------------------------------------------
// out = sampled(bf16) @ Wo^T + bo -> fp32, grid (2, 350)
// ---------------------------------------------------------------------------
__global__ __launch_bounds__(256) void out_gemm(
    const ushort_t* __restrict__ samp, const float* __restrict__ Wo,
    const float* __restrict__ bo, float* __restrict__ out) {
  extern __shared__ ushort_t smem[];
  gemm_body<0, 0>(blockIdx.x, blockIdx.y, nullptr, nullptr, samp,
                  Wo, Wo, 1 << 30, bo, nullptr, out, nullptr, 256, smem);
}

// ---------------------------------------------------------------------------
// Sampling + aggregation (unchanged from round 4/5).
// ---------------------------------------------------------------------------
__global__ __launch_bounds__(256) void msda_sample_kernel(
    const ushort_t* __restrict__ value,  // [8][QSEQ][32] bf16
    const float* __restrict__ sp,        // [Q, 192]
    const float* __restrict__ attn,      // [Q, 96]
    const float* __restrict__ refp,      // [Q, 3, 2]
    ushort_t* __restrict__ outp) {       // [Q, 256] bf16
  const int h = blockIdx.x & 7;
  const int q = (blockIdx.x >> 3) * 4 + (threadIdx.x >> 6);
  const int lane = threadIdx.x & 63;
  const int cg = lane >> 4, pt = lane & 15;
  const int ptc = pt < 12 ? pt : 11;
  const int lvl = ptc >> 2;
  const int S = lvl == 0 ? 160 : (lvl == 1 ? 80 : 40);
  const int base = lvl == 0 ? 0 : (lvl == 1 ? 25600 : 32000);

  float a = attn[q * 96 + h * 12 + ptc];
  a = pt < 12 ? a : 0.f;
  const float2 off = *(const float2*)&sp[q * 192 + h * 24 + ptc * 2];
  const float2 rp = *(const float2*)&refp[q * 6 + lvl * 2];

  const float x = fmaf(rp.x, (float)S, off.x) - 0.5f;
  const float y = fmaf(rp.y, (float)S, off.y) - 0.5f;
  const float xf = floorf(x), yf = floorf(y);
  const int x0 = (int)xf, y0 = (int)yf;
  const float wx1 = x - xf, wy1 = y - yf;

  const float wx0z = (x0 >= 0 && x0 < S) ? 1.f - wx1 : 0.f;
  const float wx1z = (x0 + 1 >= 0 && x0 + 1 < S) ? wx1 : 0.f;
  const float wy0z = (y0 >= 0 && y0 < S) ? 1.f - wy1 : 0.f;
  const float wy1z = (y0 + 1 >= 0 && y0 + 1 < S) ? wy1 : 0.f;

  const int x0c = min(max(x0, 0), S - 1);
  const int x1c = min(max(x0 + 1, 0), S - 1);
  const int y0c = min(max(y0, 0), S - 1);
  const int y1c = min(max(y0 + 1, 0), S - 1);

  const float w00 = a * wx0z * wy0z, w10 = a * wx1z * wy0z;
  const float w01 = a * wx0z * wy1z, w11 = a * wx1z * wy1z;

  const ushort_t* hb = value + ((h * QSEQ + base) << 5) + cg * 8;
  const int r0 = y0c * S, r1 = y1c * S;
  const uint4 u00 = *(const uint4*)(hb + ((r0 + x0c) << 5));
  const uint4 u10 = *(const uint4*)(hb + ((r0 + x1c) << 5));
  const uint4 u01 = *(const uint4*)(hb + ((r1 + x0c) << 5));
  const uint4 u11 = *(const uint4*)(hb + ((r1 + x1c) << 5));

  float facc[8];
  {
    const unsigned a0[4] = {u00.x, u00.y, u00.z, u00.w};
    const unsigned a1[4] = {u10.x, u10.y, u10.z, u10.w};
    const unsigned a2[4] = {u01.x, u01.y, u01.z, u01.w};
    const unsigned a3[4] = {u11.x, u11.y, u11.z, u11.w};
#pragma unroll
    for (int i = 0; i < 4; ++i) {
      float lo = __uint_as_float(a0[i] << 16) * w00;
      float hi = __uint_as_float(a0[i] & 0xFFFF0000u) * w00;
      lo = fmaf(__uint_as_float(a1[i] << 16), w10, lo);
      hi = fmaf(__uint_as_float(a1[i] & 0xFFFF0000u), w10, hi);
      lo = fmaf(__uint_as_float(a2[i] << 16), w01, lo);
      hi = fmaf(__uint_as_float(a2[i] & 0xFFFF0000u), w01, hi);
      lo = fmaf(__uint_as_float(a3[i] << 16), w11, lo);
      hi = fmaf(__uint_as_float(a3[i] & 0xFFFF0000u), w11, hi);
      facc[2 * i + 0] = lo;
      facc[2 * i + 1] = hi;
    }
  }

#pragma unroll
  for (int m = 1; m < 16; m <<= 1)
#pragma unroll
    for (int i = 0; i < 8; ++i) facc[i] += __shfl_xor(facc[i], m, 64);

  if (pt == 0) {
    ushort_t t[8];
#pragma unroll
    for (int i = 0; i < 8; ++i) t[i] = f2bf(facc[i]);
    *(uint4*)&outp[(size_t)q * 256 + h * 32 + cg * 8] = *(const uint4*)t;
  }
}

extern "C" void kernel_launch(void* const* d_in, const int* in_sizes, int n_in,
                              void* d_out, int out_size, void* d_ws, size_t ws_size,
                              hipStream_t stream) {
  const float* hidden = (const float*)d_in[0];
  const float* ehs    = (const float*)d_in[1];
  const float* pos    = (const float*)d_in[2];
  const float* refp   = (const float*)d_in[3];
  const float* Wv = (const float*)d_in[4];
  const float* bv = (const float*)d_in[5];
  const float* Ws = (const float*)d_in[6];
  const float* bs = (const float*)d_in[7];
  const float* Wa = (const float*)d_in[8];
  const float* ba = (const float*)d_in[9];
  const float* Wo = (const float*)d_in[10];
  const float* bo = (const float*)d_in[11];

  float* out  = (float*)d_out;             // [Q, 256]
  float* attn = out + (size_t)QSEQ * 256;  // [Q, 96]

  char* ws = (char*)d_ws;
  ushort_t* ws_value = (ushort_t*)ws;                  // [8][Q][32] bf16
  ushort_t* ws_outp  = ws_value + (size_t)QSEQ * 256;  // [Q,256] bf16 sampled
  float* ws_sp = (float*)(ws_outp + (size_t)QSEQ * 256);  // [Q,192] fp32

  dim3 blk(256);

  // 1. both pre-sampler GEMMs in ONE dispatch (independent work, 1750 blocks)
  pre_gemms<<<dim3(5, 350), blk, 36864, stream>>>(
      ehs, hidden, pos, Wv, bv, Wa, ba, Ws, bs, ws_value, attn, ws_sp);
  // 2. sampling
  msda_sample_kernel<<<dim3((QSEQ / 4) * 8), blk, 0, stream>>>(
      ws_value, ws_sp, attn, refp, ws_outp);
  // 3. output projection
  out_gemm<<<dim3(2, 350), blk, 28672, stream>>>(ws_outp, Wo, bo, out);
}